// Round 1
// baseline (74.379 us; speedup 1.0000x reference)
//
#include <hip/hip_runtime.h>
#include <math.h>

// Rotated 3D IoU loss — round 13 = R12 structure + dependency-chain surgery.
// R12 (75.3us, harness-verified) model: VALU issue + in-wave dependency bound,
// occupancy-insensitive. This round attacks both without structural changes:
//  (a) rectangle antisymmetry e2=-e0, e3=-e1 / f2=-f0, f3=-f1 => the 16 ISECT
//      denominators are 4 rcps up to sign (rcp(-x) == -rcp(x) exactly; sign
//      folds into a free VOP3 neg modifier). 16 -> 4 v_rcp_f32, -24 VALU.
//  (b) SITEM runtime-ticket chain -> branch-free first/second-valid priority
//      select (~15 VALU/group vs ~32, no serial counter). Group hit-count via
//      float mask sums; removes the nv-diff serialization across groups.
//  (c) sumx/sumy/nv split into 4 parallel chains (24-deep -> ~6-deep);
//      shoelace cs split into 4 accumulators (32-deep FMA -> 8-deep).
//  (d) |ab|^2 = w^2 / |ad|^2 = l^2 for PIB norms; __sincosf; payload packed
//      with v_cvt_pkrtz_f16_f32 (1 instr vs 3; f16 RTZ is MORE precise than
//      the bf16 truncation that already passed: 10-bit vs 7-bit mantissa).
// Semantics otherwise = literal emulation of the reference (incl. its
// u = -den_u/num "backward-extension" intersection mask — verified in R6).

#define RCP(x) __builtin_amdgcn_rcpf(x)

typedef _Float16 half2v __attribute__((ext_vector_type(2)));

// corner accumulate: coords always finite -> fma-with-0/1-mask is NaN-safe
#define ACCC(M, X, Y, CID) { float f_ = (M) ? 1.0f : 0.0f; \
    sx##CID = fmaf(f_, (X), sx##CID); \
    sy##CID = fmaf(f_, (Y), sy##CID); \
    nv##CID += f_; }

#define PIB_B(MX, MY, M) { float amx = (MX) - c2x0, amy = (MY) - c2y0; \
        float pab = (f0x * amx + f0y * amy) * rabB; \
        float pdd = (adxB * amx + adyB * amy) * radB; \
        M = (fabsf(pab - 0.5f) < HT) & (fabsf(pdd - 0.5f) < HT); }
#define PIB_A(MX, MY, M) { float amx = (MX) - c1x0, amy = (MY) - c1y0; \
        float pab = (e0x * amx + e0y * amy) * rabA; \
        float pdd = (adxA * amx + adyA * amy) * radA; \
        M = (fabsf(pab - 0.5f) < HT) & (fabsf(pdd - 0.5f) < HT); }

// line "intersection" with the reference's exact (backward-u) mask.
// RR is the (pre-signed) shared reciprocal of cross(f, e).
#define ISECT(X1, Y1, EX, EY, X3, Y3, FX, FY, RR, PX, PY, MM, FF) { \
        float gx_ = (X1) - (X3), gy_ = (Y1) - (Y3); \
        float dt_ = (FX) * gy_ - (FY) * gx_; \
        float du_ = (EX) * gy_ - (EY) * gx_; \
        float tt_ = dt_ * (RR), uu_ = -du_ * (RR); \
        MM = (fabsf(tt_ - 0.5f) < 0.5f) & (fabsf(uu_ - 0.5f) < 0.5f); \
        FF = (MM) ? 1.0f : 0.0f; \
        PX = (X1) + tt_ * (EX); PY = (Y1) + tt_ * (EY); }

// one box1 edge vs all 4 box2 edges: masked mean-accumulate (cndmask-guarded:
// invalid px may be inf/NaN), group count, and first/second-valid selects.
#define EDGE_GROUP(X1, Y1, EX, EY, R0, R1, R2, R3, OX0, OY0, OX1, OY1, MO0, MO1, CID) { \
        float pax, pay, pbx, pby, pcx, pcy, pdx, pdy; \
        float fa, fb, fc, fd; bool ma, mb, mc, md; \
        ISECT(X1, Y1, EX, EY, c2x0, c2y0, f0x, f0y, R0, pax, pay, ma, fa) \
        ISECT(X1, Y1, EX, EY, c2x1, c2y1, f1x, f1y, R1, pbx, pby, mb, fb) \
        ISECT(X1, Y1, EX, EY, c2x2, c2y2, f2x, f2y, R2, pcx, pcy, mc, fc) \
        ISECT(X1, Y1, EX, EY, c2x3, c2y3, f3x, f3y, R3, pdx, pdy, md, fd) \
        sx##CID += ((ma ? pax : 0.0f) + (mb ? pbx : 0.0f)) \
                 + ((mc ? pcx : 0.0f) + (md ? pdx : 0.0f)); \
        sy##CID += ((ma ? pay : 0.0f) + (mb ? pby : 0.0f)) \
                 + ((mc ? pcy : 0.0f) + (md ? pdy : 0.0f)); \
        float gcf_ = (fa + fb) + (fc + fd); \
        nv##CID += gcf_; \
        MO0 = gcf_ > 0.5f; MO1 = gcf_ > 1.5f; \
        float cdx_ = mc ? pcx : pdx,  cdy_ = mc ? pcy : pdy; \
        float bcx_ = mb ? pbx : cdx_, bcy_ = mb ? pby : cdy_; \
        OX0 = ma ? pax : bcx_;        OY0 = ma ? pay : bcy_; \
        float s2x_ = mb ? cdx_ : pdx, s2y_ = mb ? cdy_ : pdy; \
        OX1 = ma ? bcx_ : s2x_;       OY1 = ma ? bcy_ : s2y_; }

#define ANGPACK(K) { float xc = vx##K - mx_, yc = vy##K - my_; \
        float tt = xc * RCP(fmaxf(fabsf(xc) + fabsf(yc), 1e-38f)); \
        float key = copysignf(1.0f - tt, yc); \
        ang##K = m##K ? key : 1e6f; \
        pk##K = __builtin_bit_cast(unsigned, __builtin_amdgcn_cvt_pkrtz(xc, yc)); }
#define CE(A, B) { bool sw = ang##A > ang##B; \
        float mn = fminf(ang##A, ang##B), mx2 = fmaxf(ang##A, ang##B); \
        ang##A = mn; ang##B = mx2; \
        unsigned ta = pk##A; pk##A = sw ? pk##B : pk##A; pk##B = sw ? ta : pk##B; }
#define PAD(K) { pk##K = (ang##K > 5e5f) ? pk0 : pk##K; }
#define UPX(K) float ux##K, uy##K; { half2v h_ = __builtin_bit_cast(half2v, pk##K); \
        ux##K = (float)h_.x; uy##K = (float)h_.y; }
#define SHOE(A, B, C) { cs##C = fmaf(ux##A, uy##B, cs##C); \
                        cs##C = fmaf(-uy##A, ux##B, cs##C); }

__device__ __forceinline__ float riou_item(
    const float* __restrict__ pred, const float* __restrict__ tgt, float wg, int idx)
{
    const float* pp = pred + 7 * idx;
    const float* qq = tgt + 7 * idx;
    float p0 = pp[0], p1 = pp[1], p2 = pp[2], p3 = pp[3], p4 = pp[4], p5 = pp[5], p6 = pp[6];
    float q0 = qq[0], q1 = qq[1], q2 = qq[2], q3 = qq[3], q4 = qq[4], q5 = qq[5], q6 = qq[6];

    // ---- decode_fcos_obb (loc = 0) ----
    float w1 = p0 + p3, l1 = p1 + p4, h1 = p2 + p5;
    float oz1 = (p5 - p2) * 0.5f;
    float ox1 = (p3 - p0) * 0.5f, oy1 = (p4 - p1) * 0.5f;
    float sA, cA; __sincosf(p6, &sA, &cA);
    float cx1 = ox1 * cA - oy1 * sA, cy1 = ox1 * sA + oy1 * cA;

    float w2 = q0 + q3, l2 = q1 + q4, h2 = q2 + q5;
    float oz2 = (q5 - q2) * 0.5f;
    float ox2 = (q3 - q0) * 0.5f, oy2 = (q4 - q1) * 0.5f;
    float sB, cB; __sincosf(q6, &sB, &cB);
    float cx2 = ox2 * cB - oy2 * sB, cy2 = ox2 * sB + oy2 * cB;

    float vol1 = w1 * l1 * h1, vol2 = w2 * l2 * h2;
    float zo = fmaxf(fminf(oz1 + h1 * 0.5f, oz2 + h2 * 0.5f) -
                     fmaxf(oz1 - h1 * 0.5f, oz2 - h2 * 0.5f), 0.0f);

    // ---- corners: signs (+,+),(-,+),(-,-),(+,-) of (w/2, l/2), rotated ----
    float hw1 = 0.5f * w1, hl1 = 0.5f * l1;
    float c1x0 =  hw1 * cA - hl1 * sA + cx1, c1y0 =  hw1 * sA + hl1 * cA + cy1;
    float c1x1 = -hw1 * cA - hl1 * sA + cx1, c1y1 = -hw1 * sA + hl1 * cA + cy1;
    float c1x2 = -hw1 * cA + hl1 * sA + cx1, c1y2 = -hw1 * sA - hl1 * cA + cy1;
    float c1x3 =  hw1 * cA + hl1 * sA + cx1, c1y3 =  hw1 * sA - hl1 * cA + cy1;
    float hw2 = 0.5f * w2, hl2 = 0.5f * l2;
    float c2x0 =  hw2 * cB - hl2 * sB + cx2, c2y0 =  hw2 * sB + hl2 * cB + cy2;
    float c2x1 = -hw2 * cB - hl2 * sB + cx2, c2y1 = -hw2 * sB + hl2 * cB + cy2;
    float c2x2 = -hw2 * cB + hl2 * sB + cx2, c2y2 = -hw2 * sB - hl2 * cB + cy2;
    float c2x3 =  hw2 * cB + hl2 * sB + cx2, c2y3 =  hw2 * sB - hl2 * cB + cy2;

    // ---- edge direction vectors (also serve PIB ab-vectors) ----
    float e0x = c1x1 - c1x0, e0y = c1y1 - c1y0;
    float e1x = c1x2 - c1x1, e1y = c1y2 - c1y1;
    float e2x = c1x3 - c1x2, e2y = c1y3 - c1y2;
    float e3x = c1x0 - c1x3, e3y = c1y0 - c1y3;
    float f0x = c2x1 - c2x0, f0y = c2y1 - c2y0;
    float f1x = c2x2 - c2x1, f1y = c2y2 - c2y1;
    float f2x = c2x3 - c2x2, f2y = c2y3 - c2y2;
    float f3x = c2x0 - c2x3, f3y = c2y0 - c2y3;

    // ---- 4-way split mean accumulators ----
    float sx0 = 0.f, sx1 = 0.f, sx2 = 0.f, sx3 = 0.f;
    float sy0 = 0.f, sy1 = 0.f, sy2 = 0.f, sy3 = 0.f;
    float nv0 = 0.f, nv1 = 0.f, nv2 = 0.f, nv3 = 0.f;

    // ---- point-in-box masks; |ab|^2 = w^2, |ad|^2 = l^2 (rectangle) ----
    const float HT = 0.5f + 1e-6f;
    float adxB = c2x3 - c2x0, adyB = c2y3 - c2y0;
    float rabB = RCP(w2 * w2), radB = RCP(l2 * l2);
    bool mA0, mA1, mA2, mA3;
    PIB_B(c1x0, c1y0, mA0) PIB_B(c1x1, c1y1, mA1)
    PIB_B(c1x2, c1y2, mA2) PIB_B(c1x3, c1y3, mA3)
    ACCC(mA0, c1x0, c1y0, 0) ACCC(mA1, c1x1, c1y1, 1)
    ACCC(mA2, c1x2, c1y2, 2) ACCC(mA3, c1x3, c1y3, 3)
    float adxA = c1x3 - c1x0, adyA = c1y3 - c1y0;
    float rabA = RCP(w1 * w1), radA = RCP(l1 * l1);
    bool mB0, mB1, mB2, mB3;
    PIB_A(c2x0, c2y0, mB0) PIB_A(c2x1, c2y1, mB1)
    PIB_A(c2x2, c2y2, mB2) PIB_A(c2x3, c2y3, mB3)
    ACCC(mB0, c2x0, c2y0, 0) ACCC(mB1, c2x1, c2y1, 1)
    ACCC(mB2, c2x2, c2y2, 2) ACCC(mB3, c2x3, c2y3, 3)

    // ---- shared reciprocals: num(g,j) = cross(f_j, e_g); e2=-e0 f2=-f0 etc.
    //      => 4 rcps, signs folded into free neg modifiers at the consumers.
    float r00 = RCP(f0y * e0x - f0x * e0y);
    float r01 = RCP(f1y * e0x - f1x * e0y);
    float r10 = RCP(f0y * e1x - f0x * e1y);
    float r11 = RCP(f1y * e1x - f1x * e1y);

    // ---- edge-edge "intersections", reference's exact (buggy-u) mask ----
    bool m8, m9, m10, m11, m12, m13, m14, m15;
    float vx8, vy8, vx9, vy9, vx10, vy10, vx11, vy11;
    float vx12, vy12, vx13, vy13, vx14, vy14, vx15, vy15;
    EDGE_GROUP(c1x0, c1y0, e0x, e0y,  r00,  r01, -r00, -r01,
               vx8,  vy8,  vx9,  vy9,  m8,  m9,  0)
    EDGE_GROUP(c1x1, c1y1, e1x, e1y,  r10,  r11, -r10, -r11,
               vx10, vy10, vx11, vy11, m10, m11, 1)
    EDGE_GROUP(c1x2, c1y2, e2x, e2y, -r00, -r01,  r00,  r01,
               vx12, vy12, vx13, vy13, m12, m13, 2)
    EDGE_GROUP(c1x3, c1y3, e3x, e3y, -r10, -r11,  r10,  r11,
               vx14, vy14, vx15, vy15, m14, m15, 3)

    float vx0 = c1x0, vy0 = c1y0, vx1 = c1x1, vy1 = c1y1;
    float vx2 = c1x2, vy2 = c1y2, vx3 = c1x3, vy3 = c1y3;
    float vx4 = c2x0, vy4 = c2y0, vx5 = c2x1, vy5 = c2y1;
    float vx6 = c2x2, vy6 = c2y2, vx7 = c2x3, vy7 = c2y3;
    bool m0 = mA0, m1 = mA1, m2 = mA2, m3 = mA3;
    bool m4 = mB0, m5 = mB1, m6 = mB2, m7 = mB3;

    // ---- center; branch-free diamond key (monotone in atan2, verified) ----
    float nv = (nv0 + nv1) + (nv2 + nv3);
    float inv_nv = RCP(fmaxf(nv, 1.0f));
    float mx_ = ((sx0 + sx1) + (sx2 + sx3)) * inv_nv;
    float my_ = ((sy0 + sy1) + (sy2 + sy3)) * inv_nv;
    float ang0, ang1, ang2, ang3, ang4, ang5, ang6, ang7;
    float ang8, ang9, ang10, ang11, ang12, ang13, ang14, ang15;
    unsigned pk0, pk1, pk2, pk3, pk4, pk5, pk6, pk7;
    unsigned pk8, pk9, pk10, pk11, pk12, pk13, pk14, pk15;
    ANGPACK(0) ANGPACK(1) ANGPACK(2) ANGPACK(3)
    ANGPACK(4) ANGPACK(5) ANGPACK(6) ANGPACK(7)
    ANGPACK(8) ANGPACK(9) ANGPACK(10) ANGPACK(11)
    ANGPACK(12) ANGPACK(13) ANGPACK(14) ANGPACK(15)

    // ---- Batcher odd-even mergesort, 16 elems, 63 CEs; 5 inst/CE ----
    CE(0,1) CE(2,3) CE(4,5) CE(6,7) CE(8,9) CE(10,11) CE(12,13) CE(14,15)
    CE(0,2) CE(1,3) CE(4,6) CE(5,7) CE(8,10) CE(9,11) CE(12,14) CE(13,15)
    CE(1,2) CE(5,6) CE(9,10) CE(13,14)
    CE(0,4) CE(1,5) CE(2,6) CE(3,7) CE(8,12) CE(9,13) CE(10,14) CE(11,15)
    CE(2,4) CE(3,5) CE(10,12) CE(11,13)
    CE(1,2) CE(3,4) CE(5,6) CE(9,10) CE(11,12) CE(13,14)
    CE(0,8) CE(1,9) CE(2,10) CE(3,11) CE(4,12) CE(5,13) CE(6,14) CE(7,15)
    CE(4,8) CE(5,9) CE(6,10) CE(7,11)
    CE(2,4) CE(3,5) CE(6,8) CE(7,9) CE(10,12) CE(11,13)
    CE(1,2) CE(3,4) CE(5,6) CE(7,8) CE(9,10) CE(11,12) CE(13,14)

    // ---- ref padding: invalid slots (key 1e6) sorted last ----
    PAD(1) PAD(2) PAD(3) PAD(4) PAD(5) PAD(6) PAD(7) PAD(8)
    PAD(9) PAD(10) PAD(11) PAD(12) PAD(13) PAD(14) PAD(15)

    // ---- unpack + cyclic shoelace (4 parallel accumulators) ----
    UPX(0) UPX(1) UPX(2) UPX(3) UPX(4) UPX(5) UPX(6) UPX(7)
    UPX(8) UPX(9) UPX(10) UPX(11) UPX(12) UPX(13) UPX(14) UPX(15)
    float cs0 = 0.f, cs1 = 0.f, cs2 = 0.f, cs3 = 0.f;
    SHOE(0,1,0)  SHOE(1,2,0)  SHOE(2,3,0)   SHOE(3,4,0)
    SHOE(4,5,1)  SHOE(5,6,1)  SHOE(6,7,1)   SHOE(7,8,1)
    SHOE(8,9,2)  SHOE(9,10,2) SHOE(10,11,2) SHOE(11,12,2)
    SHOE(12,13,3) SHOE(13,14,3) SHOE(14,15,3) SHOE(15,0,3)
    float cs = (cs0 + cs1) + (cs2 + cs3);
    float inter = 0.5f * fabsf(cs);

    // ---- loss (iou2d*u2 cancels u2 -> inter3d = inter*zo) ----
    float inter3d = inter * zo;
    float u3d = vol1 + vol2 - inter3d;
    float iouf = (inter3d + 1.0f) * RCP(u3d + 1.0f);
    return -__logf(iouf) * wg;
}

__global__ __launch_bounds__(256, 2) void riou_loss_kernel(
    const float* __restrict__ pred, const float* __restrict__ tgt,
    const float* __restrict__ wgt, float* __restrict__ ws, int n)
{
    // two elements per thread, index-clamped (NO branch around the bodies:
    // both chains live in one basic block so the scheduler interleaves them)
    int i0 = blockIdx.x * 512 + threadIdx.x;
    int i1 = i0 + 256;
    int idx0 = min(i0, n - 1), idx1 = min(i1, n - 1);
    float wg0 = (i0 < n) ? wgt[idx0] : 0.0f;
    float wg1 = (i1 < n) ? wgt[idx1] : 0.0f;
    float loss = riou_item(pred, tgt, wg0, idx0)
               + riou_item(pred, tgt, wg1, idx1);

    // ---- block reduction -> ONE partial-sum store per block ----
#pragma unroll
    for (int off = 32; off > 0; off >>= 1)
        loss += __shfl_down(loss, off, 64);
    __shared__ float wsum[4];
    int lane = threadIdx.x & 63, wid = threadIdx.x >> 6;
    if (lane == 0) wsum[wid] = loss;
    __syncthreads();
    if (threadIdx.x == 0)
        ws[blockIdx.x] = wsum[0] + wsum[1] + wsum[2] + wsum[3];
}

__global__ __launch_bounds__(256) void riou_reduce_kernel(
    const float* __restrict__ ws, float* __restrict__ out, int nb)
{
    float s = 0.0f;
    for (int t = threadIdx.x; t < nb; t += 256) s += ws[t];
#pragma unroll
    for (int off = 32; off > 0; off >>= 1)
        s += __shfl_down(s, off, 64);
    __shared__ float wsum[4];
    int lane = threadIdx.x & 63, wid = threadIdx.x >> 6;
    if (lane == 0) wsum[wid] = s;
    __syncthreads();
    if (threadIdx.x == 0)
        out[0] = wsum[0] + wsum[1] + wsum[2] + wsum[3];
}

extern "C" void kernel_launch(void* const* d_in, const int* in_sizes, int n_in,
                              void* d_out, int out_size, void* d_ws, size_t ws_size,
                              hipStream_t stream) {
    const float* pred = (const float*)d_in[0];
    const float* tgt  = (const float*)d_in[1];
    const float* wgt  = (const float*)d_in[2];
    float* out = (float*)d_out;
    float* ws  = (float*)d_ws;
    int n = in_sizes[2];

    int grid = (n + 511) / 512;   // 489 for n=250000
    riou_loss_kernel<<<grid, 256, 0, stream>>>(pred, tgt, wgt, ws, n);
    riou_reduce_kernel<<<1, 256, 0, stream>>>(ws, out, grid);
}

// Round 2
// 73.803 us; speedup vs baseline: 1.0078x; 1.0078x over previous
//
#include <hip/hip_runtime.h>
#include <math.h>

// Rotated 3D IoU loss — round 14 = R13 numerics, TLP instead of ILP.
// R13 post-mortem: dep-chain surgery gave only −1.2% => issue/dep model wrong
// or masked. Key realization: total waves are FIXED by items/thread —
// at 2 items/thread the grid (489 blocks = 1953 waves / 1024 SIMDs) pins
// residency at 1.9 waves/SIMD regardless of launch_bounds, so the prior
// session's "occupancy-insensitive" A/B (launch_bounds at fixed grid) was
// confounded. ILP×2 helping (R12) is the latency-bound signature; TLP is the
// cheaper way to buy the same overlap: 1 item/thread halves per-wave live
// registers (~90 VGPR peak, fits 128 => 4 waves/SIMD) and halves code size.
// This round: 1 item/thread, 977 blocks, launch_bounds(256,4). Numerics are
// byte-identical to R13 (absmax 0.0) — isolates the occupancy variable.

#define RCP(x) __builtin_amdgcn_rcpf(x)

typedef _Float16 half2v __attribute__((ext_vector_type(2)));

// corner accumulate: coords always finite -> fma-with-0/1-mask is NaN-safe
#define ACCC(M, X, Y, CID) { float f_ = (M) ? 1.0f : 0.0f; \
    sx##CID = fmaf(f_, (X), sx##CID); \
    sy##CID = fmaf(f_, (Y), sy##CID); \
    nv##CID += f_; }

#define PIB_B(MX, MY, M) { float amx = (MX) - c2x0, amy = (MY) - c2y0; \
        float pab = (f0x * amx + f0y * amy) * rabB; \
        float pdd = (adxB * amx + adyB * amy) * radB; \
        M = (fabsf(pab - 0.5f) < HT) & (fabsf(pdd - 0.5f) < HT); }
#define PIB_A(MX, MY, M) { float amx = (MX) - c1x0, amy = (MY) - c1y0; \
        float pab = (e0x * amx + e0y * amy) * rabA; \
        float pdd = (adxA * amx + adyA * amy) * radA; \
        M = (fabsf(pab - 0.5f) < HT) & (fabsf(pdd - 0.5f) < HT); }

// line "intersection" with the reference's exact (backward-u) mask.
// RR is the (pre-signed) shared reciprocal of cross(f, e).
#define ISECT(X1, Y1, EX, EY, X3, Y3, FX, FY, RR, PX, PY, MM, FF) { \
        float gx_ = (X1) - (X3), gy_ = (Y1) - (Y3); \
        float dt_ = (FX) * gy_ - (FY) * gx_; \
        float du_ = (EX) * gy_ - (EY) * gx_; \
        float tt_ = dt_ * (RR), uu_ = -du_ * (RR); \
        MM = (fabsf(tt_ - 0.5f) < 0.5f) & (fabsf(uu_ - 0.5f) < 0.5f); \
        FF = (MM) ? 1.0f : 0.0f; \
        PX = (X1) + tt_ * (EX); PY = (Y1) + tt_ * (EY); }

// one box1 edge vs all 4 box2 edges: masked mean-accumulate (cndmask-guarded:
// invalid px may be inf/NaN), group count, and first/second-valid selects.
#define EDGE_GROUP(X1, Y1, EX, EY, R0, R1, R2, R3, OX0, OY0, OX1, OY1, MO0, MO1, CID) { \
        float pax, pay, pbx, pby, pcx, pcy, pdx, pdy; \
        float fa, fb, fc, fd; bool ma, mb, mc, md; \
        ISECT(X1, Y1, EX, EY, c2x0, c2y0, f0x, f0y, R0, pax, pay, ma, fa) \
        ISECT(X1, Y1, EX, EY, c2x1, c2y1, f1x, f1y, R1, pbx, pby, mb, fb) \
        ISECT(X1, Y1, EX, EY, c2x2, c2y2, f2x, f2y, R2, pcx, pcy, mc, fc) \
        ISECT(X1, Y1, EX, EY, c2x3, c2y3, f3x, f3y, R3, pdx, pdy, md, fd) \
        sx##CID += ((ma ? pax : 0.0f) + (mb ? pbx : 0.0f)) \
                 + ((mc ? pcx : 0.0f) + (md ? pdx : 0.0f)); \
        sy##CID += ((ma ? pay : 0.0f) + (mb ? pby : 0.0f)) \
                 + ((mc ? pcy : 0.0f) + (md ? pdy : 0.0f)); \
        float gcf_ = (fa + fb) + (fc + fd); \
        nv##CID += gcf_; \
        MO0 = gcf_ > 0.5f; MO1 = gcf_ > 1.5f; \
        float cdx_ = mc ? pcx : pdx,  cdy_ = mc ? pcy : pdy; \
        float bcx_ = mb ? pbx : cdx_, bcy_ = mb ? pby : cdy_; \
        OX0 = ma ? pax : bcx_;        OY0 = ma ? pay : bcy_; \
        float s2x_ = mb ? cdx_ : pdx, s2y_ = mb ? cdy_ : pdy; \
        OX1 = ma ? bcx_ : s2x_;       OY1 = ma ? bcy_ : s2y_; }

#define ANGPACK(K) { float xc = vx##K - mx_, yc = vy##K - my_; \
        float tt = xc * RCP(fmaxf(fabsf(xc) + fabsf(yc), 1e-38f)); \
        float key = copysignf(1.0f - tt, yc); \
        ang##K = m##K ? key : 1e6f; \
        pk##K = __builtin_bit_cast(unsigned, __builtin_amdgcn_cvt_pkrtz(xc, yc)); }
#define CE(A, B) { bool sw = ang##A > ang##B; \
        float mn = fminf(ang##A, ang##B), mx2 = fmaxf(ang##A, ang##B); \
        ang##A = mn; ang##B = mx2; \
        unsigned ta = pk##A; pk##A = sw ? pk##B : pk##A; pk##B = sw ? ta : pk##B; }
#define PAD(K) { pk##K = (ang##K > 5e5f) ? pk0 : pk##K; }
#define UPX(K) float ux##K, uy##K; { half2v h_ = __builtin_bit_cast(half2v, pk##K); \
        ux##K = (float)h_.x; uy##K = (float)h_.y; }
#define SHOE(A, B, C) { cs##C = fmaf(ux##A, uy##B, cs##C); \
                        cs##C = fmaf(-uy##A, ux##B, cs##C); }

__device__ __forceinline__ float riou_item(
    const float* __restrict__ pred, const float* __restrict__ tgt, float wg, int idx)
{
    const float* pp = pred + 7 * idx;
    const float* qq = tgt + 7 * idx;
    float p0 = pp[0], p1 = pp[1], p2 = pp[2], p3 = pp[3], p4 = pp[4], p5 = pp[5], p6 = pp[6];
    float q0 = qq[0], q1 = qq[1], q2 = qq[2], q3 = qq[3], q4 = qq[4], q5 = qq[5], q6 = qq[6];

    // ---- decode_fcos_obb (loc = 0) ----
    float w1 = p0 + p3, l1 = p1 + p4, h1 = p2 + p5;
    float oz1 = (p5 - p2) * 0.5f;
    float ox1 = (p3 - p0) * 0.5f, oy1 = (p4 - p1) * 0.5f;
    float sA, cA; __sincosf(p6, &sA, &cA);
    float cx1 = ox1 * cA - oy1 * sA, cy1 = ox1 * sA + oy1 * cA;

    float w2 = q0 + q3, l2 = q1 + q4, h2 = q2 + q5;
    float oz2 = (q5 - q2) * 0.5f;
    float ox2 = (q3 - q0) * 0.5f, oy2 = (q4 - q1) * 0.5f;
    float sB, cB; __sincosf(q6, &sB, &cB);
    float cx2 = ox2 * cB - oy2 * sB, cy2 = ox2 * sB + oy2 * cB;

    float vol1 = w1 * l1 * h1, vol2 = w2 * l2 * h2;
    float zo = fmaxf(fminf(oz1 + h1 * 0.5f, oz2 + h2 * 0.5f) -
                     fmaxf(oz1 - h1 * 0.5f, oz2 - h2 * 0.5f), 0.0f);

    // ---- corners: signs (+,+),(-,+),(-,-),(+,-) of (w/2, l/2), rotated ----
    float hw1 = 0.5f * w1, hl1 = 0.5f * l1;
    float c1x0 =  hw1 * cA - hl1 * sA + cx1, c1y0 =  hw1 * sA + hl1 * cA + cy1;
    float c1x1 = -hw1 * cA - hl1 * sA + cx1, c1y1 = -hw1 * sA + hl1 * cA + cy1;
    float c1x2 = -hw1 * cA + hl1 * sA + cx1, c1y2 = -hw1 * sA - hl1 * cA + cy1;
    float c1x3 =  hw1 * cA + hl1 * sA + cx1, c1y3 =  hw1 * sA - hl1 * cA + cy1;
    float hw2 = 0.5f * w2, hl2 = 0.5f * l2;
    float c2x0 =  hw2 * cB - hl2 * sB + cx2, c2y0 =  hw2 * sB + hl2 * cB + cy2;
    float c2x1 = -hw2 * cB - hl2 * sB + cx2, c2y1 = -hw2 * sB + hl2 * cB + cy2;
    float c2x2 = -hw2 * cB + hl2 * sB + cx2, c2y2 = -hw2 * sB - hl2 * cB + cy2;
    float c2x3 =  hw2 * cB + hl2 * sB + cx2, c2y3 =  hw2 * sB - hl2 * cB + cy2;

    // ---- edge direction vectors (also serve PIB ab-vectors) ----
    float e0x = c1x1 - c1x0, e0y = c1y1 - c1y0;
    float e1x = c1x2 - c1x1, e1y = c1y2 - c1y1;
    float e2x = c1x3 - c1x2, e2y = c1y3 - c1y2;
    float e3x = c1x0 - c1x3, e3y = c1y0 - c1y3;
    float f0x = c2x1 - c2x0, f0y = c2y1 - c2y0;
    float f1x = c2x2 - c2x1, f1y = c2y2 - c2y1;
    float f2x = c2x3 - c2x2, f2y = c2y3 - c2y2;
    float f3x = c2x0 - c2x3, f3y = c2y0 - c2y3;

    // ---- 4-way split mean accumulators ----
    float sx0 = 0.f, sx1 = 0.f, sx2 = 0.f, sx3 = 0.f;
    float sy0 = 0.f, sy1 = 0.f, sy2 = 0.f, sy3 = 0.f;
    float nv0 = 0.f, nv1 = 0.f, nv2 = 0.f, nv3 = 0.f;

    // ---- point-in-box masks; |ab|^2 = w^2, |ad|^2 = l^2 (rectangle) ----
    const float HT = 0.5f + 1e-6f;
    float adxB = c2x3 - c2x0, adyB = c2y3 - c2y0;
    float rabB = RCP(w2 * w2), radB = RCP(l2 * l2);
    bool mA0, mA1, mA2, mA3;
    PIB_B(c1x0, c1y0, mA0) PIB_B(c1x1, c1y1, mA1)
    PIB_B(c1x2, c1y2, mA2) PIB_B(c1x3, c1y3, mA3)
    ACCC(mA0, c1x0, c1y0, 0) ACCC(mA1, c1x1, c1y1, 1)
    ACCC(mA2, c1x2, c1y2, 2) ACCC(mA3, c1x3, c1y3, 3)
    float adxA = c1x3 - c1x0, adyA = c1y3 - c1y0;
    float rabA = RCP(w1 * w1), radA = RCP(l1 * l1);
    bool mB0, mB1, mB2, mB3;
    PIB_A(c2x0, c2y0, mB0) PIB_A(c2x1, c2y1, mB1)
    PIB_A(c2x2, c2y2, mB2) PIB_A(c2x3, c2y3, mB3)
    ACCC(mB0, c2x0, c2y0, 0) ACCC(mB1, c2x1, c2y1, 1)
    ACCC(mB2, c2x2, c2y2, 2) ACCC(mB3, c2x3, c2y3, 3)

    // ---- shared reciprocals: num(g,j) = cross(f_j, e_g); e2=-e0 f2=-f0 etc.
    //      => 4 rcps, signs folded into free neg modifiers at the consumers.
    float r00 = RCP(f0y * e0x - f0x * e0y);
    float r01 = RCP(f1y * e0x - f1x * e0y);
    float r10 = RCP(f0y * e1x - f0x * e1y);
    float r11 = RCP(f1y * e1x - f1x * e1y);

    // ---- edge-edge "intersections", reference's exact (buggy-u) mask ----
    bool m8, m9, m10, m11, m12, m13, m14, m15;
    float vx8, vy8, vx9, vy9, vx10, vy10, vx11, vy11;
    float vx12, vy12, vx13, vy13, vx14, vy14, vx15, vy15;
    EDGE_GROUP(c1x0, c1y0, e0x, e0y,  r00,  r01, -r00, -r01,
               vx8,  vy8,  vx9,  vy9,  m8,  m9,  0)
    EDGE_GROUP(c1x1, c1y1, e1x, e1y,  r10,  r11, -r10, -r11,
               vx10, vy10, vx11, vy11, m10, m11, 1)
    EDGE_GROUP(c1x2, c1y2, e2x, e2y, -r00, -r01,  r00,  r01,
               vx12, vy12, vx13, vy13, m12, m13, 2)
    EDGE_GROUP(c1x3, c1y3, e3x, e3y, -r10, -r11,  r10,  r11,
               vx14, vy14, vx15, vy15, m14, m15, 3)

    float vx0 = c1x0, vy0 = c1y0, vx1 = c1x1, vy1 = c1y1;
    float vx2 = c1x2, vy2 = c1y2, vx3 = c1x3, vy3 = c1y3;
    float vx4 = c2x0, vy4 = c2y0, vx5 = c2x1, vy5 = c2y1;
    float vx6 = c2x2, vy6 = c2y2, vx7 = c2x3, vy7 = c2y3;
    bool m0 = mA0, m1 = mA1, m2 = mA2, m3 = mA3;
    bool m4 = mB0, m5 = mB1, m6 = mB2, m7 = mB3;

    // ---- center; branch-free diamond key (monotone in atan2, verified) ----
    float nv = (nv0 + nv1) + (nv2 + nv3);
    float inv_nv = RCP(fmaxf(nv, 1.0f));
    float mx_ = ((sx0 + sx1) + (sx2 + sx3)) * inv_nv;
    float my_ = ((sy0 + sy1) + (sy2 + sy3)) * inv_nv;
    float ang0, ang1, ang2, ang3, ang4, ang5, ang6, ang7;
    float ang8, ang9, ang10, ang11, ang12, ang13, ang14, ang15;
    unsigned pk0, pk1, pk2, pk3, pk4, pk5, pk6, pk7;
    unsigned pk8, pk9, pk10, pk11, pk12, pk13, pk14, pk15;
    ANGPACK(0) ANGPACK(1) ANGPACK(2) ANGPACK(3)
    ANGPACK(4) ANGPACK(5) ANGPACK(6) ANGPACK(7)
    ANGPACK(8) ANGPACK(9) ANGPACK(10) ANGPACK(11)
    ANGPACK(12) ANGPACK(13) ANGPACK(14) ANGPACK(15)

    // ---- Batcher odd-even mergesort, 16 elems, 63 CEs; 5 inst/CE ----
    CE(0,1) CE(2,3) CE(4,5) CE(6,7) CE(8,9) CE(10,11) CE(12,13) CE(14,15)
    CE(0,2) CE(1,3) CE(4,6) CE(5,7) CE(8,10) CE(9,11) CE(12,14) CE(13,15)
    CE(1,2) CE(5,6) CE(9,10) CE(13,14)
    CE(0,4) CE(1,5) CE(2,6) CE(3,7) CE(8,12) CE(9,13) CE(10,14) CE(11,15)
    CE(2,4) CE(3,5) CE(10,12) CE(11,13)
    CE(1,2) CE(3,4) CE(5,6) CE(9,10) CE(11,12) CE(13,14)
    CE(0,8) CE(1,9) CE(2,10) CE(3,11) CE(4,12) CE(5,13) CE(6,14) CE(7,15)
    CE(4,8) CE(5,9) CE(6,10) CE(7,11)
    CE(2,4) CE(3,5) CE(6,8) CE(7,9) CE(10,12) CE(11,13)
    CE(1,2) CE(3,4) CE(5,6) CE(7,8) CE(9,10) CE(11,12) CE(13,14)

    // ---- ref padding: invalid slots (key 1e6) sorted last ----
    PAD(1) PAD(2) PAD(3) PAD(4) PAD(5) PAD(6) PAD(7) PAD(8)
    PAD(9) PAD(10) PAD(11) PAD(12) PAD(13) PAD(14) PAD(15)

    // ---- unpack + cyclic shoelace (4 parallel accumulators) ----
    UPX(0) UPX(1) UPX(2) UPX(3) UPX(4) UPX(5) UPX(6) UPX(7)
    UPX(8) UPX(9) UPX(10) UPX(11) UPX(12) UPX(13) UPX(14) UPX(15)
    float cs0 = 0.f, cs1 = 0.f, cs2 = 0.f, cs3 = 0.f;
    SHOE(0,1,0)  SHOE(1,2,0)  SHOE(2,3,0)   SHOE(3,4,0)
    SHOE(4,5,1)  SHOE(5,6,1)  SHOE(6,7,1)   SHOE(7,8,1)
    SHOE(8,9,2)  SHOE(9,10,2) SHOE(10,11,2) SHOE(11,12,2)
    SHOE(12,13,3) SHOE(13,14,3) SHOE(14,15,3) SHOE(15,0,3)
    float cs = (cs0 + cs1) + (cs2 + cs3);
    float inter = 0.5f * fabsf(cs);

    // ---- loss (iou2d*u2 cancels u2 -> inter3d = inter*zo) ----
    float inter3d = inter * zo;
    float u3d = vol1 + vol2 - inter3d;
    float iouf = (inter3d + 1.0f) * RCP(u3d + 1.0f);
    return -__logf(iouf) * wg;
}

__global__ __launch_bounds__(256, 4) void riou_loss_kernel(
    const float* __restrict__ pred, const float* __restrict__ tgt,
    const float* __restrict__ wgt, float* __restrict__ ws, int n)
{
    // ONE element per thread: total waves = 3906 -> ~3.8 waves/SIMD resident
    // (vs 1.9 with 2 items/thread). Per-wave VGPR demand halves; target <=128
    // so (256,4) residency is register-feasible. TLP replaces R12's ILP.
    int i0 = blockIdx.x * 256 + threadIdx.x;
    int idx0 = min(i0, n - 1);
    float wg0 = (i0 < n) ? wgt[idx0] : 0.0f;
    float loss = riou_item(pred, tgt, wg0, idx0);

    // ---- block reduction -> ONE partial-sum store per block ----
#pragma unroll
    for (int off = 32; off > 0; off >>= 1)
        loss += __shfl_down(loss, off, 64);
    __shared__ float wsum[4];
    int lane = threadIdx.x & 63, wid = threadIdx.x >> 6;
    if (lane == 0) wsum[wid] = loss;
    __syncthreads();
    if (threadIdx.x == 0)
        ws[blockIdx.x] = wsum[0] + wsum[1] + wsum[2] + wsum[3];
}

__global__ __launch_bounds__(256) void riou_reduce_kernel(
    const float* __restrict__ ws, float* __restrict__ out, int nb)
{
    float s = 0.0f;
    for (int t = threadIdx.x; t < nb; t += 256) s += ws[t];
#pragma unroll
    for (int off = 32; off > 0; off >>= 1)
        s += __shfl_down(s, off, 64);
    __shared__ float wsum[4];
    int lane = threadIdx.x & 63, wid = threadIdx.x >> 6;
    if (lane == 0) wsum[wid] = s;
    __syncthreads();
    if (threadIdx.x == 0)
        out[0] = wsum[0] + wsum[1] + wsum[2] + wsum[3];
}

extern "C" void kernel_launch(void* const* d_in, const int* in_sizes, int n_in,
                              void* d_out, int out_size, void* d_ws, size_t ws_size,
                              hipStream_t stream) {
    const float* pred = (const float*)d_in[0];
    const float* tgt  = (const float*)d_in[1];
    const float* wgt  = (const float*)d_in[2];
    float* out = (float*)d_out;
    float* ws  = (float*)d_ws;
    int n = in_sizes[2];

    int grid = (n + 255) / 256;   // 977 for n=250000
    riou_loss_kernel<<<grid, 256, 0, stream>>>(pred, tgt, wgt, ws, n);
    riou_reduce_kernel<<<1, 256, 0, stream>>>(ws, out, grid);
}